// Round 10
// baseline (131.671 us; speedup 1.0000x reference)
//
#include <hip/hip_runtime.h>

#define B_TOT 32768
#define OC 30
#define HID 100
#define TAGS 36

// ws layout (dwords):
#define WS_TH  0          // fp16x2[6000]  T tables
#define WS_FC1 6000       // u32[23296]    fc1 B-frag packs
#define WS_OUT 29296      // u32[3072]     out B-frag packs
#define WS_F   40960      // u32[32768*208] fp16 feature rows (27.3 MB)

typedef __attribute__((ext_vector_type(8))) _Float16 half8;
typedef __attribute__((ext_vector_type(2))) _Float16 h2v;
typedef __attribute__((ext_vector_type(4))) float f32x4;

__device__ inline half8 ash8(uint4 u) {
    union { uint4 a; half8 b; } v; v.a = u; return v.b;
}
__device__ inline unsigned int h2u(h2v h) {
    union { h2v a; unsigned int b; } v; v.a = h; return v.b;
}
__device__ inline h2v u2h(unsigned int u) {
    union { unsigned int a; h2v b; } v; v.a = u; return v.b;
}
__device__ inline unsigned int pk_f16(float a, float b) {
    h2v h; h.x = (_Float16)a; h.y = (_Float16)b; return h2u(h);
}

// ---------------- prep: fp16 T tables + fp16 MFMA B-frag packs ----------------
__global__ void prep(const float* __restrict__ conv_w,   // (30,32,3)
                     const float* __restrict__ char_emb, // (100,32)
                     const float* __restrict__ fc1_w,    // (100,400)
                     const float* __restrict__ out_w,    // (36,100)
                     unsigned int* __restrict__ ws) {
    int idx = blockIdx.x * 256 + threadIdx.x;
    if (idx < 6000) {
        // TH[k][c][20 dwords]: row = 40 fp16 (32 used) -> 80 B rows
        int rd = idx % 20, row = idx / 20;
        int c = row % 100, k = row / 100;
        float v[2];
        #pragma unroll
        for (int e = 0; e < 2; ++e) {
            int oc = rd * 2 + e;
            float s = 0.f;
            if (oc < OC) {
                for (int ce = 0; ce < 32; ++ce)
                    s += char_emb[c * 32 + ce] * conv_w[(oc * 32 + ce) * 3 + k];
            }
            v[e] = s;
        }
        ws[WS_TH + idx] = pk_f16(v[0], v[1]);
    } else if (idx < 6000 + 23296) {
        // fc1 B-frag chunks: [(nt*13+ks)][lane][dw] ; n=lane&15, k=ks*32+(lane>>4)*8+dw*2
        int t = idx - 6000;
        int dw = t & 3, lane = (t >> 2) & 63, chunk = t >> 8;
        int ks = chunk % 13, nt = chunk / 13;
        int j = nt * 16 + (lane & 15);
        int k = ks * 32 + (lane >> 4) * 8 + dw * 2;
        float a = (j < HID && k     < 400) ? fc1_w[j * 400 + k]     : 0.f;
        float b = (j < HID && k + 1 < 400) ? fc1_w[j * 400 + k + 1] : 0.f;
        ws[WS_FC1 + t] = pk_f16(a, b);
    } else if (idx < 29296 + 3072) {
        int t = idx - 29296;
        int dw = t & 3, lane = (t >> 2) & 63, chunk = t >> 8;
        int ks = chunk % 4, nt = chunk / 4;
        int j = nt * 16 + (lane & 15);
        int k = ks * 32 + (lane >> 4) * 8 + dw * 2;
        float a = (j < TAGS && k     < HID) ? out_w[j * 100 + k]     : 0.f;
        float b = (j < TAGS && k + 1 < HID) ? out_w[j * 100 + k + 1] : 0.f;
        ws[WS_OUT + t] = pk_f16(a, b);
    }
}

// ---------------- feat: emb gather + conv/maxpool -> fp16 F rows (32 items/block, 512 thr) ----
__global__ __launch_bounds__(512)
void feat(const int*   __restrict__ input,   // (B, 105)
          const float* __restrict__ emb,     // (WV, 50)
          const float* __restrict__ conv_b,  // (30)
          unsigned int* __restrict__ ws)
{
    __shared__ unsigned int Ths[6000];        // fp16 T tables, 24000 B

    const int tid   = threadIdx.x;
    const int item0 = blockIdx.x * 32;
    unsigned int* Fg = ws + WS_F;

    for (int idx = tid; idx < 6000; idx += 512) Ths[idx] = ws[WS_TH + idx];
    __syncthreads();

    // ---- zero K-pad dwords 200..207 per item (32*8 = 256 tasks) ----
    if (tid < 256) Fg[(item0 + (tid >> 3)) * 208 + 200 + (tid & 7)] = 0;

    // ---- word embeddings (32*125 = 4000 tasks; ids in [0,100) -> L1-hot) ----
    for (int idx = tid; idx < 4000; idx += 512) {
        int ph = idx % 25;
        int w  = (idx / 25) % 5;
        int i  = idx / 125;
        int wid = input[(item0 + i) * 105 + w * 21];
        float2 e = *(const float2*)&emb[wid * 50 + ph * 2];
        Fg[(item0 + i) * 208 + w * 40 + ph] = pk_f16(e.x, e.y);
    }

    // ---- conv + maxpool: 4 lanes per (i,w), lane = 8 oc; 160 tasks over 128 groups ----
    {
        const int q4  = tid & 3;
        const int oc0 = q4 * 8;
        h2v bias[4];
        #pragma unroll
        for (int d = 0; d < 4; ++d) {
            int a = oc0 + 2 * d, b = a + 1;
            bias[d].x = (_Float16)(a < OC ? conv_b[a] : 0.f);
            bias[d].y = (_Float16)(b < OC ? conv_b[b] : 0.f);
        }
        for (int task = tid >> 2; task < 160; task += 128) {
            int i = task / 5, w = task % 5;
            const int* cp = &input[(item0 + i) * 105 + w * 21 + 1];
            int c[20];
            #pragma unroll
            for (int p = 0; p < 20; ++p) c[p] = cp[p];
            h2v m[4];
            #pragma unroll
            for (int d = 0; d < 4; ++d) { m[d].x = (_Float16)(-30000.f); m[d].y = (_Float16)(-30000.f); }
            #pragma unroll 6
            for (int p = 0; p < 18; ++p) {
                uint4 ra = *(const uint4*)&Ths[c[p    ] * 20        + q4 * 4];
                uint4 rb = *(const uint4*)&Ths[c[p + 1] * 20 + 2000 + q4 * 4];
                uint4 rc = *(const uint4*)&Ths[c[p + 2] * 20 + 4000 + q4 * 4];
                unsigned int* pa = (unsigned int*)&ra;
                unsigned int* pb = (unsigned int*)&rb;
                unsigned int* pc = (unsigned int*)&rc;
                #pragma unroll
                for (int d = 0; d < 4; ++d) {
                    h2v s = u2h(pa[d]) + u2h(pb[d]) + u2h(pc[d]);
                    m[d] = __builtin_elementwise_max(m[d], s);
                }
            }
            int base = (item0 + i) * 208 + w * 40 + 25 + q4 * 4;
            Fg[base]     = h2u(m[0] + bias[0]);
            Fg[base + 1] = h2u(m[1] + bias[1]);
            Fg[base + 2] = h2u(m[2] + bias[2]);
            if (q4 < 3) Fg[base + 3] = h2u(m[3] + bias[3]);
        }
    }
}

// ---------------- gemm: 2 waves per 16-item group, N-split; grid 2048 ----------------
__global__ __launch_bounds__(128)
void gemm(const float* __restrict__ fc1_b,   // (100)
          const float* __restrict__ out_b,   // (36)
          const unsigned int* __restrict__ ws,
          float*       __restrict__ out)     // (B, 36)
{
    __shared__ unsigned int Hh[16 * 68];      // h fp16x2, 4352 B

    const int tid  = threadIdx.x;
    const int wv   = tid >> 6;                // 0 or 1
    const int lane = tid & 63;
    const int ln15 = lane & 15;
    const int quad = lane >> 4;
    const int item0 = blockIdx.x * 16;
    const unsigned int* Fg = ws + WS_F;

    // ---- fc1: wave0 -> n-tiles 0..3, wave1 -> 4..6 ----
    const int t0 = wv ? 4 : 0;
    const int tn = wv ? 3 : 4;
    f32x4 acc[4];
    #pragma unroll
    for (int t = 0; t < 4; ++t) acc[t] = f32x4{0, 0, 0, 0};
    {
        const uint4* wp = (const uint4*)(ws + WS_FC1);
        const unsigned int* arow = Fg + (item0 + ln15) * 208 + quad * 4;
        for (int ks = 0; ks < 13; ++ks) {
            half8 a = ash8(*(const uint4*)(arow + ks * 16));
            #pragma unroll
            for (int t = 0; t < 4; ++t) {
                if (t < tn) {
                    uint4 bv = wp[((t0 + t) * 13 + ks) * 64 + lane];
                    acc[t] = __builtin_amdgcn_mfma_f32_16x16x32_f16(a, ash8(bv), acc[t], 0, 0, 0);
                }
            }
        }
    }

    // ---- epilogue: tanh -> Hh; wave1 zeros K-pad ----
    if (wv == 1) {
        for (int t2 = lane; t2 < 224; t2 += 64) {
            int i = t2 / 14, d = t2 % 14;
            Hh[i * 68 + 50 + d] = 0;
        }
    }
    {
        unsigned short* Hs = (unsigned short*)Hh;
        #pragma unroll
        for (int t = 0; t < 4; ++t) {
            if (t < tn) {
                int j = (t0 + t) * 16 + ln15;
                if (j < HID) {
                    float bj = fc1_b[j];
                    #pragma unroll
                    for (int r = 0; r < 4; ++r) {
                        int it = quad * 4 + r;
                        float hv = tanhf(acc[t][r] + bj);
                        _Float16 h = (_Float16)hv;
                        Hs[it * 136 + j] = *reinterpret_cast<unsigned short*>(&h);
                    }
                }
            }
        }
    }
    __syncthreads();

    // ---- out layer: wave0 -> tiles 0,1 ; wave1 -> tile 2 ----
    {
        const int ot0 = wv ? 2 : 0;
        const int otn = wv ? 1 : 2;
        f32x4 oacc[2];
        #pragma unroll
        for (int t = 0; t < 2; ++t) oacc[t] = f32x4{0, 0, 0, 0};
        const uint4* wpo = (const uint4*)(ws + WS_OUT);
        const int aoff = ln15 * 68 + quad * 4;
        #pragma unroll
        for (int ks = 0; ks < 4; ++ks) {
            half8 a = ash8(*(const uint4*)&Hh[aoff + ks * 16]);
            #pragma unroll
            for (int t = 0; t < 2; ++t) {
                if (t < otn) {
                    uint4 bv = wpo[((ot0 + t) * 4 + ks) * 64 + lane];
                    oacc[t] = __builtin_amdgcn_mfma_f32_16x16x32_f16(a, ash8(bv), oacc[t], 0, 0, 0);
                }
            }
        }
        #pragma unroll
        for (int t = 0; t < 2; ++t) {
            if (t < otn) {
                int o = (ot0 + t) * 16 + ln15;
                if (o < TAGS) {
                    float bo = out_b[o];
                    #pragma unroll
                    for (int r = 0; r < 4; ++r) {
                        int it = item0 + quad * 4 + r;
                        out[it * TAGS + o] = oacc[t][r] + bo;
                    }
                }
            }
        }
    }
}

extern "C" void kernel_launch(void* const* d_in, const int* in_sizes, int n_in,
                              void* d_out, int out_size, void* d_ws, size_t ws_size,
                              hipStream_t stream) {
    const int*   input  = (const int*)  d_in[0];
    const float* emb    = (const float*)d_in[1];
    const float* char_e = (const float*)d_in[2];
    const float* conv_w = (const float*)d_in[3];
    const float* conv_b = (const float*)d_in[4];
    const float* fc1_w  = (const float*)d_in[5];
    const float* fc1_b  = (const float*)d_in[6];
    const float* out_w  = (const float*)d_in[7];
    const float* out_b  = (const float*)d_in[8];
    unsigned int* ws = (unsigned int*)d_ws;

    prep<<<127, 256, 0, stream>>>(conv_w, char_e, fc1_w, out_w, ws);
    feat<<<B_TOT / 32, 512, 0, stream>>>(input, emb, conv_b, ws);
    gemm<<<B_TOT / 16, 128, 0, stream>>>(fc1_b, out_b, ws, (float*)d_out);
}

// Round 11
// 131.341 us; speedup vs baseline: 1.0025x; 1.0025x over previous
//
#include <hip/hip_runtime.h>

#define B_TOT 32768
#define OC 30
#define HID 100
#define TAGS 36

// ws layout (dwords):
#define WS_TH  0          // fp16x2[6000]  T tables
#define WS_FC1 6000       // u32[23296]    fc1 B-frag packs
#define WS_OUT 29296      // u32[3072]     out B-frag packs
#define WS_F   40960      // u32[32768*208] fp16 feature rows (27.3 MB)

typedef __attribute__((ext_vector_type(8))) _Float16 half8;
typedef __attribute__((ext_vector_type(2))) _Float16 h2v;
typedef __attribute__((ext_vector_type(4))) float f32x4;

__device__ inline half8 ash8(uint4 u) {
    union { uint4 a; half8 b; } v; v.a = u; return v.b;
}
__device__ inline unsigned int h2u(h2v h) {
    union { h2v a; unsigned int b; } v; v.a = h; return v.b;
}
__device__ inline h2v u2h(unsigned int u) {
    union { unsigned int a; h2v b; } v; v.a = u; return v.b;
}
__device__ inline unsigned int pk_f16(float a, float b) {
    h2v h; h.x = (_Float16)a; h.y = (_Float16)b; return h2u(h);
}

// ---------------- prep: fp16 T tables + fp16 MFMA B-frag packs ----------------
__global__ void prep(const float* __restrict__ conv_w,   // (30,32,3)
                     const float* __restrict__ char_emb, // (100,32)
                     const float* __restrict__ fc1_w,    // (100,400)
                     const float* __restrict__ out_w,    // (36,100)
                     unsigned int* __restrict__ ws) {
    int idx = blockIdx.x * 256 + threadIdx.x;
    if (idx < 6000) {
        // TH[k][c][20 dwords]: row = 40 fp16 (32 used) -> 80 B rows
        int rd = idx % 20, row = idx / 20;
        int c = row % 100, k = row / 100;
        float v[2];
        #pragma unroll
        for (int e = 0; e < 2; ++e) {
            int oc = rd * 2 + e;
            float s = 0.f;
            if (oc < OC) {
                for (int ce = 0; ce < 32; ++ce)
                    s += char_emb[c * 32 + ce] * conv_w[(oc * 32 + ce) * 3 + k];
            }
            v[e] = s;
        }
        ws[WS_TH + idx] = pk_f16(v[0], v[1]);
    } else if (idx < 6000 + 23296) {
        // fc1 B-frag chunks: [(nt*13+ks)][lane][dw] ; n=lane&15, k=ks*32+(lane>>4)*8+dw*2
        int t = idx - 6000;
        int dw = t & 3, lane = (t >> 2) & 63, chunk = t >> 8;
        int ks = chunk % 13, nt = chunk / 13;
        int j = nt * 16 + (lane & 15);
        int k = ks * 32 + (lane >> 4) * 8 + dw * 2;
        float a = (j < HID && k     < 400) ? fc1_w[j * 400 + k]     : 0.f;
        float b = (j < HID && k + 1 < 400) ? fc1_w[j * 400 + k + 1] : 0.f;
        ws[WS_FC1 + t] = pk_f16(a, b);
    } else if (idx < 29296 + 3072) {
        int t = idx - 29296;
        int dw = t & 3, lane = (t >> 2) & 63, chunk = t >> 8;
        int ks = chunk % 4, nt = chunk / 4;
        int j = nt * 16 + (lane & 15);
        int k = ks * 32 + (lane >> 4) * 8 + dw * 2;
        float a = (j < TAGS && k     < HID) ? out_w[j * 100 + k]     : 0.f;
        float b = (j < TAGS && k + 1 < HID) ? out_w[j * 100 + k + 1] : 0.f;
        ws[WS_OUT + t] = pk_f16(a, b);
    }
}

// ---------------- feat: emb gather + conv/maxpool -> fp16 F rows in global ----------------
__global__ __launch_bounds__(256)
void feat(const int*   __restrict__ input,   // (B, 105)
          const float* __restrict__ emb,     // (WV, 50)
          const float* __restrict__ conv_b,  // (30)
          unsigned int* __restrict__ ws)
{
    __shared__ unsigned int Ths[6000];        // fp16 T tables, 24000 B

    const int tid   = threadIdx.x;
    const int item0 = blockIdx.x * 16;
    unsigned int* Fg = ws + WS_F;

    for (int idx = tid; idx < 6000; idx += 256) Ths[idx] = ws[WS_TH + idx];
    __syncthreads();

    // ---- zero K-pad dwords 200..207 per item ----
    if (tid < 128) Fg[(item0 + (tid >> 3)) * 208 + 200 + (tid & 7)] = 0;

    // ---- word embeddings (ids in [0,100) -> emb slab is L1-hot) ----
    for (int idx = tid; idx < 2000; idx += 256) {
        int ph = idx % 25;
        int w  = (idx / 25) % 5;
        int i  = idx / 125;
        int wid = input[(item0 + i) * 105 + w * 21];
        float2 e = *(const float2*)&emb[wid * 50 + ph * 2];
        Fg[(item0 + i) * 208 + w * 40 + ph] = pk_f16(e.x, e.y);
    }

    // ---- conv + maxpool: 4 lanes per (i,w), lane = 8 oc ----
    {
        const int q4  = tid & 3;
        const int oc0 = q4 * 8;
        h2v bias[4];
        #pragma unroll
        for (int d = 0; d < 4; ++d) {
            int a = oc0 + 2 * d, b = a + 1;
            bias[d].x = (_Float16)(a < OC ? conv_b[a] : 0.f);
            bias[d].y = (_Float16)(b < OC ? conv_b[b] : 0.f);
        }
        for (int task = tid >> 2; task < 80; task += 64) {
            int i = task / 5, w = task % 5;
            const int* cp = &input[(item0 + i) * 105 + w * 21 + 1];
            int c[20];
            #pragma unroll
            for (int p = 0; p < 20; ++p) c[p] = cp[p];
            h2v m[4];
            #pragma unroll
            for (int d = 0; d < 4; ++d) { m[d].x = (_Float16)(-30000.f); m[d].y = (_Float16)(-30000.f); }
            #pragma unroll 6
            for (int p = 0; p < 18; ++p) {
                uint4 ra = *(const uint4*)&Ths[c[p    ] * 20        + q4 * 4];
                uint4 rb = *(const uint4*)&Ths[c[p + 1] * 20 + 2000 + q4 * 4];
                uint4 rc = *(const uint4*)&Ths[c[p + 2] * 20 + 4000 + q4 * 4];
                unsigned int* pa = (unsigned int*)&ra;
                unsigned int* pb = (unsigned int*)&rb;
                unsigned int* pc = (unsigned int*)&rc;
                #pragma unroll
                for (int d = 0; d < 4; ++d) {
                    h2v s = u2h(pa[d]) + u2h(pb[d]) + u2h(pc[d]);
                    m[d] = __builtin_elementwise_max(m[d], s);
                }
            }
            int base = (item0 + i) * 208 + w * 40 + 25 + q4 * 4;
            Fg[base]     = h2u(m[0] + bias[0]);
            Fg[base + 1] = h2u(m[1] + bias[1]);
            Fg[base + 2] = h2u(m[2] + bias[2]);
            if (q4 < 3) Fg[base + 3] = h2u(m[3] + bias[3]);
        }
    }
}

// ---------------- gemm: fc1 (MFMA, A from global) + tanh + out layer ----------------
__global__ __launch_bounds__(256)
void gemm(const float* __restrict__ fc1_b,   // (100)
          const float* __restrict__ out_b,   // (36)
          const unsigned int* __restrict__ ws,
          float*       __restrict__ out)     // (B, 36)
{
    __shared__ unsigned int Hh[4][16 * 68];   // per-wave h slice, 4352 B each

    const int tid  = threadIdx.x;
    const int wv   = tid >> 6;
    const int lane = tid & 63;
    const int ln15 = lane & 15;
    const int quad = lane >> 4;
    const int item0 = blockIdx.x * 64 + wv * 16;
    unsigned int* Hw = &Hh[wv][0];
    const unsigned int* Fg = ws + WS_F;

    // ---- fc1: 13 K-steps, A streamed from global, 7 n-tiles ----
    f32x4 acc[7];
    #pragma unroll
    for (int t = 0; t < 7; ++t) acc[t] = f32x4{0, 0, 0, 0};
    {
        const uint4* wp = (const uint4*)(ws + WS_FC1);
        const unsigned int* arow = Fg + (item0 + ln15) * 208 + quad * 4;
        for (int ks = 0; ks < 13; ++ks) {
            half8 a = ash8(*(const uint4*)(arow + ks * 16));
            #pragma unroll
            for (int t = 0; t < 7; ++t) {
                uint4 bv = wp[(t * 13 + ks) * 64 + lane];
                acc[t] = __builtin_amdgcn_mfma_f32_16x16x32_f16(a, ash8(bv), acc[t], 0, 0, 0);
            }
        }
    }

    // ---- epilogue: tanh -> Hh (C-layout -> A-layout via LDS), zero K-pad ----
    {
        for (int t2 = lane; t2 < 224; t2 += 64) {
            int i = t2 / 14, d = t2 % 14;
            Hw[i * 68 + 50 + d] = 0;
        }
        unsigned short* Hs = (unsigned short*)Hw;
        #pragma unroll
        for (int t = 0; t < 7; ++t) {
            int j = t * 16 + ln15;
            if (j < HID) {
                float bj = fc1_b[j];
                #pragma unroll
                for (int r = 0; r < 4; ++r) {
                    int it = quad * 4 + r;
                    float hv = tanhf(acc[t][r] + bj);
                    _Float16 h = (_Float16)hv;
                    Hs[it * 136 + j] = *reinterpret_cast<unsigned short*>(&h);
                }
            }
        }
    }
    // same-wave LDS writes are visible to same-wave reads in-order: no barrier

    // ---- out layer: 3 n-tiles, K=128 ----
    {
        f32x4 oacc[3];
        #pragma unroll
        for (int t = 0; t < 3; ++t) oacc[t] = f32x4{0, 0, 0, 0};
        const uint4* wpo = (const uint4*)(ws + WS_OUT);
        const int aoff = ln15 * 68 + quad * 4;
        #pragma unroll
        for (int ks = 0; ks < 4; ++ks) {
            half8 a = ash8(*(const uint4*)&Hw[aoff + ks * 16]);
            #pragma unroll
            for (int t = 0; t < 3; ++t) {
                uint4 bv = wpo[(t * 4 + ks) * 64 + lane];
                oacc[t] = __builtin_amdgcn_mfma_f32_16x16x32_f16(a, ash8(bv), oacc[t], 0, 0, 0);
            }
        }
        #pragma unroll
        for (int t = 0; t < 3; ++t) {
            int o = t * 16 + ln15;
            if (o < TAGS) {
                float bo = out_b[o];
                #pragma unroll
                for (int r = 0; r < 4; ++r) {
                    int it = item0 + quad * 4 + r;
                    out[it * TAGS + o] = oacc[t][r] + bo;
                }
            }
        }
    }
}

extern "C" void kernel_launch(void* const* d_in, const int* in_sizes, int n_in,
                              void* d_out, int out_size, void* d_ws, size_t ws_size,
                              hipStream_t stream) {
    const int*   input  = (const int*)  d_in[0];
    const float* emb    = (const float*)d_in[1];
    const float* char_e = (const float*)d_in[2];
    const float* conv_w = (const float*)d_in[3];
    const float* conv_b = (const float*)d_in[4];
    const float* fc1_w  = (const float*)d_in[5];
    const float* fc1_b  = (const float*)d_in[6];
    const float* out_w  = (const float*)d_in[7];
    const float* out_b  = (const float*)d_in[8];
    unsigned int* ws = (unsigned int*)d_ws;

    prep<<<127, 256, 0, stream>>>(conv_w, char_e, fc1_w, out_w, ws);
    feat<<<B_TOT / 16, 256, 0, stream>>>(input, emb, conv_b, ws);
    gemm<<<B_TOT / 64, 256, 0, stream>>>(fc1_b, out_b, ws, (float*)d_out);
}